// Round 1
// baseline (678.213 us; speedup 1.0000x reference)
//
#include <hip/hip_runtime.h>

typedef unsigned short u16;
typedef unsigned int u32;
typedef unsigned long long u64;
typedef __attribute__((ext_vector_type(4)))  int  i32x4;
typedef __attribute__((ext_vector_type(16))) int  i32x16;
typedef __attribute__((ext_vector_type(16))) char i8x16;

#define NPTS 131072
#define DIM  256
#define KC   2048
#define HALF_NT 32   // centroid tiles (of 32) per block: 1024 centroids

// 3-level fixed point: v = S1*q1 + S2*q2 + S3*q3 + eps, |eps| <= S3/2 ~ 4.8e-7
// Ratio 254 => rint(r*INV) in [-127,127]: no clamp cascade.
// Identity S1*S3 == S2*S2 lets q2q2, q1q3, q3q1 share one accumulator.
constexpr float S1  = 0.0625f;                 // 127*S1 = 7.94 > max|N(0,1)|
constexpr float S2  = S1 / 254.0f;
constexpr float S3  = S2 * S2 / S1;            // = S2/254
constexpr float IS1 = 16.0f;
constexpr float IS2 = 4064.0f;                 // 254/S1
constexpr float IS3 = 1.0f / S3;
constexpr float W_A = S1 * S1;
// epilogue compares in W_A-scaled units: score' = 0.5*csq/W_A - (A + B/254 + C/254^2)
constexpr float R2  = 1.0f / 254.0f;
constexpr float R3  = 1.0f / 64516.0f;

__device__ inline void quant3(float v, char& q1, char& q2, char& q3) {
    float a = fminf(fmaxf(rintf(v * IS1), -127.f), 127.f);
    float r1 = fmaf(-a, S1, v);                // exact (pow2 scale)
    float b = fminf(fmaxf(rintf(r1 * IS2), -127.f), 127.f);
    float r2 = fmaf(-b, S2, r1);               // ~1-ulp error, absorbed by q3
    float c = fminf(fmaxf(rintf(r2 * IS3), -127.f), 127.f);
    q1 = (char)a; q2 = (char)b; q3 = (char)c;
}

// global -> LDS direct DMA, 16B per lane (wave-uniform base + lane*16)
#define GLD16(gsrc, ldst) \
    __builtin_amdgcn_global_load_lds( \
        (const __attribute__((address_space(1))) void*)(gsrc), \
        (__attribute__((address_space(3))) void*)(ldst), 16, 0, 0)

// ---------------------------------------------------------------------------
// Centroid prep: 3-level i8 split in MFMA-A-fragment order + scaled 0.5||c||^2.
// Per tile g (32 centroids): chunk s = dim/16, addr = ((g*16+s)*32+row)*16+b.
// Level l at byte offset l*KC*DIM. Also zeroes hist (blocks 0..7).
// ---------------------------------------------------------------------------
__global__ void cprep_kernel(const float* __restrict__ cen,
                             char* __restrict__ c_q,
                             float* __restrict__ c_sq,
                             int* __restrict__ hist) {
    if (blockIdx.x < 8) hist[blockIdx.x * 256 + threadIdx.x] = 0;
    const int lane = threadIdx.x & 63;
    const int wv   = threadIdx.x >> 6;
    const int n    = blockIdx.x * 4 + wv;               // centroid row
    float4 v = ((const float4*)(cen + (size_t)n * DIM))[lane];  // dims lane*4..+3
    float ss = v.x * v.x + v.y * v.y + v.z * v.z + v.w * v.w;
    float fv[4] = {v.x, v.y, v.z, v.w};
    char q1[4], q2[4], q3[4];
#pragma unroll
    for (int j = 0; j < 4; ++j) quant3(fv[j], q1[j], q2[j], q3[j]);
    const int g = n >> 5, r32 = n & 31;
    const int s = lane >> 2;                             // chunk = dim/16
    const size_t base = ((size_t)((g * 16 + s) * 32 + r32)) * 16 + (lane & 3) * 4;
    u32 p1 = (u32)(unsigned char)q1[0] | ((u32)(unsigned char)q1[1] << 8) |
             ((u32)(unsigned char)q1[2] << 16) | ((u32)(unsigned char)q1[3] << 24);
    u32 p2 = (u32)(unsigned char)q2[0] | ((u32)(unsigned char)q2[1] << 8) |
             ((u32)(unsigned char)q2[2] << 16) | ((u32)(unsigned char)q2[3] << 24);
    u32 p3 = (u32)(unsigned char)q3[0] | ((u32)(unsigned char)q3[1] << 8) |
             ((u32)(unsigned char)q3[2] << 16) | ((u32)(unsigned char)q3[3] << 24);
    *(u32*)(c_q + base) = p1;
    *(u32*)(c_q + (size_t)KC * DIM + base) = p2;
    *(u32*)(c_q + (size_t)2 * KC * DIM + base) = p3;
#pragma unroll
    for (int off = 32; off > 0; off >>= 1) ss += __shfl_xor(ss, off);
    if (lane == 0) c_sq[n] = 0.5f * ss / W_A;            // pre-scaled for epilogue
}

// ---------------------------------------------------------------------------
// Assignment: per wave 32 points x 1024 centroids (half), 6 i8 MFMAs per tile:
//   accA += q1c*q1x                        (weight 1      in W_A units)
//   accB += q1c*q2x + q2c*q1x              (weight 1/254)
//   accC += q2c*q2x + q1c*q3x + q3c*q1x    (weight 1/254^2)
// Grid = 2048 blocks (point-chunk x centroid-half). Halving the per-block work
// flattens the residency tail: grid 1024 was exactly 4 blocks/CU with only 3
// residency slots (LDS 48KB x 3 = 144KB; VGPR caps 3 waves/SIMD), so 1/4 of
// the work ran at 1 block/CU. Halves merge via packed u64 atomicMin
// (sortable_score<<32 | idx) preserving argmin lowest-index tie semantics.
// ---------------------------------------------------------------------------
__global__ __launch_bounds__(256, 3) void assign_kernel(
    const float* __restrict__ x, const char* __restrict__ c_q,
    const float* __restrict__ c_sq, u64* __restrict__ best_key) {
    __shared__ char lds_c[2 * 24576];   // buf: [q1 8KB][q2 8KB][q3 8KB] x 2

    const int tid  = threadIdx.x;
    const int lane = tid & 63;
    const int wv   = tid >> 6;
    const int l31  = lane & 31;
    const int kh   = lane >> 5;         // 16-dim half of the 32-dim k-tile
    const int pc   = blockIdx.x >> 1;   // point chunk (128 points)
    const int h    = blockIdx.x & 1;    // centroid half (1024 centroids)

    // ---- quantize this lane's point (dims kt*32+kh*16 .. +15 per kt) ----
    const int m = pc * 128 + wv * 32 + l31;
    const float4* xr = (const float4*)(x + (size_t)m * DIM);
    i8x16 xq1[8], xq2[8], xq3[8];
#pragma unroll
    for (int kt = 0; kt < 8; ++kt) {
        float tmp[16];
#pragma unroll
        for (int j = 0; j < 4; ++j) {
            float4 f = xr[kt * 8 + kh * 4 + j];
            tmp[j * 4 + 0] = f.x; tmp[j * 4 + 1] = f.y;
            tmp[j * 4 + 2] = f.z; tmp[j * 4 + 3] = f.w;
        }
        i8x16 v1, v2, v3;
#pragma unroll
        for (int j = 0; j < 16; ++j) {
            char a, b, c;
            quant3(tmp[j], a, b, c);
            v1[j] = a; v2[j] = b; v3[j] = c;
        }
        xq1[kt] = v1; xq2[kt] = v2; xq3[kt] = v3;
    }

    const float4* csq4 = (const float4*)c_sq;
    float best = 3.4e38f;
    int bidx = 0;

    const size_t ho = (size_t)h * (HALF_NT * 8192);      // half offset per level
    const char* cl1 = c_q + ho;
    const char* cl2 = c_q + (size_t)KC * DIM + ho;
    const char* cl3 = c_q + (size_t)2 * KC * DIM + ho;
    // prologue: DMA tile 0 of this half (6 x 16B per thread)
    {
        GLD16(cl1 + tid * 16,         lds_c + tid * 16);
        GLD16(cl1 + (tid + 256) * 16, lds_c + (tid + 256) * 16);
        GLD16(cl2 + tid * 16,         lds_c + 8192 + tid * 16);
        GLD16(cl2 + (tid + 256) * 16, lds_c + 8192 + (tid + 256) * 16);
        GLD16(cl3 + tid * 16,         lds_c + 16384 + tid * 16);
        GLD16(cl3 + (tid + 256) * 16, lds_c + 16384 + (tid + 256) * 16);
    }

    for (int t = 0; t < HALF_NT; ++t) {
        const int b = t & 1;
        __syncthreads();   // drains own DMA (vmcnt 0) -> tile t visible to all
        if (t < HALF_NT - 1) {  // prefetch t+1 into other buffer; hidden by compute
            const size_t so = (size_t)(t + 1) * 8192;
            char* d = lds_c + (b ^ 1) * 24576;
            GLD16(cl1 + so + tid * 16,         d + tid * 16);
            GLD16(cl1 + so + (tid + 256) * 16, d + (tid + 256) * 16);
            GLD16(cl2 + so + tid * 16,         d + 8192 + tid * 16);
            GLD16(cl2 + so + (tid + 256) * 16, d + 8192 + (tid + 256) * 16);
            GLD16(cl3 + so + tid * 16,         d + 16384 + tid * 16);
            GLD16(cl3 + so + (tid + 256) * 16, d + 16384 + (tid + 256) * 16);
        }

        i32x16 accA = {}, accB = {}, accC = {};
        const char* cb = lds_c + b * 24576;
#pragma unroll
        for (int kt = 0; kt < 8; ++kt) {
            const int off = ((kt * 2 + kh) * 32 + l31) * 16;
            i32x4 c1 = __builtin_bit_cast(i32x4, *(const i8x16*)(cb + off));
            i32x4 c2 = __builtin_bit_cast(i32x4, *(const i8x16*)(cb + 8192 + off));
            i32x4 c3 = __builtin_bit_cast(i32x4, *(const i8x16*)(cb + 16384 + off));
            i32x4 x1 = __builtin_bit_cast(i32x4, xq1[kt]);
            i32x4 x2 = __builtin_bit_cast(i32x4, xq2[kt]);
            i32x4 x3 = __builtin_bit_cast(i32x4, xq3[kt]);
            // interleaved so same-accumulator MFMAs aren't back-to-back
            accA = __builtin_amdgcn_mfma_i32_32x32x32_i8(c1, x1, accA, 0, 0, 0);
            accB = __builtin_amdgcn_mfma_i32_32x32x32_i8(c1, x2, accB, 0, 0, 0);
            accC = __builtin_amdgcn_mfma_i32_32x32x32_i8(c2, x2, accC, 0, 0, 0);
            accB = __builtin_amdgcn_mfma_i32_32x32x32_i8(c2, x1, accB, 0, 0, 0);
            accC = __builtin_amdgcn_mfma_i32_32x32x32_i8(c1, x3, accC, 0, 0, 0);
            accC = __builtin_amdgcn_mfma_i32_32x32x32_i8(c3, x1, accC, 0, 0, 0);
        }

        // score' = csq_s - (A + B/254 + C/254^2) ; D row = (reg&3)+8*(reg>>2)+4*kh
        const int nt = h * HALF_NT + t;
#pragma unroll
        for (int bq = 0; bq < 4; ++bq) {
            float4 cs = csq4[nt * 8 + 2 * bq + kh];
            const int n0 = nt * 32 + 8 * bq + 4 * kh;
            float csa[4] = {cs.x, cs.y, cs.z, cs.w};
#pragma unroll
            for (int r = 0; r < 4; ++r) {
                const int idx = bq * 4 + r;
                float dot = fmaf((float)accB[idx], R2,
                            fmaf((float)accC[idx], R3, (float)accA[idx]));
                float v = csa[r] - dot;
                if (v < best) { best = v; bidx = n0 + r; }
            }
        }
    }

    // merge the lane pair holding the other 16 centroid rows for point m
    float oval = __shfl_xor(best, 32);
    int   oidx = __shfl_xor(bidx, 32);
    if (oval < best || (oval == best && oidx < bidx)) { best = oval; bidx = oidx; }
    if (lane < 32) {
        // pack (score, idx) into a sortable u64: min over keys == (min score,
        // then min idx). Monotone float->u32: flip sign bit (+) / all bits (-).
        u32 sb = __float_as_uint(best);
        sb = (sb & 0x80000000u) ? ~sb : (sb | 0x80000000u);
        u64 key = ((u64)sb << 32) | (u32)bidx;
        atomicMin(&best_key[m], key);
    }
}

// Materialize winners: assigns + histogram (after both halves merged).
__global__ void resolve_kernel(const u64* __restrict__ best_key,
                               int* __restrict__ assigns,
                               int* __restrict__ hist) {
    const int m = blockIdx.x * 256 + threadIdx.x;
    const int idx = (int)(u32)(best_key[m] & 0xffffffffu);
    assigns[m] = idx;
    atomicAdd(&hist[idx], 1);
}

// Exclusive prefix sum over KC=2048 counts; one block of 256 threads x 8 each.
__global__ void scan_kernel(const int* __restrict__ hist,
                            int* __restrict__ base_,
                            int* __restrict__ cursor) {
    __shared__ int tmp[256];
    const int tid = threadIdx.x;
    int v[8], s = 0;
#pragma unroll
    for (int j = 0; j < 8; ++j) { v[j] = hist[tid * 8 + j]; s += v[j]; }
    tmp[tid] = s;
    __syncthreads();
    for (int off = 1; off < 256; off <<= 1) {
        int t = (tid >= off) ? tmp[tid - off] : 0;
        __syncthreads();
        tmp[tid] += t;
        __syncthreads();
    }
    int ex = tmp[tid] - s;
#pragma unroll
    for (int j = 0; j < 8; ++j) {
        base_[tid * 8 + j] = ex;
        cursor[tid * 8 + j] = ex;
        ex += v[j];
    }
}

__global__ void reorder_kernel(const int* __restrict__ assigns,
                               int* __restrict__ cursor,
                               int* __restrict__ order) {
    const int p = blockIdx.x * 256 + threadIdx.x;
    const int a = assigns[p];
    int pos = atomicAdd(&cursor[a], 1);
    order[pos] = p;
}

// ---------------------------------------------------------------------------
// Skew-immune segmented reduce: each block owns 256 consecutive rows of the
// SORTED order array; thread t owns dim t (coalesced 1KB row reads). Flush to
// sums[] with atomics only at cluster boundaries (block-uniform branches).
// ---------------------------------------------------------------------------
__global__ void reduce_kernel(const float* __restrict__ x,
                              const int* __restrict__ order,
                              const int* __restrict__ assigns,
                              float* __restrict__ sums) {
    const int tid = threadIdx.x;
    const int r0 = blockIdx.x * 256;
    float acc = 0.f;
    int cur = assigns[order[r0]];
    for (int r = 0; r < 256; r += 4) {
        int p0 = order[r0 + r + 0], p1 = order[r0 + r + 1];
        int p2 = order[r0 + r + 2], p3 = order[r0 + r + 3];
        float v0 = x[(size_t)p0 * DIM + tid];
        float v1 = x[(size_t)p1 * DIM + tid];
        float v2 = x[(size_t)p2 * DIM + tid];
        float v3 = x[(size_t)p3 * DIM + tid];
        int a0 = assigns[p0], a1 = assigns[p1], a2 = assigns[p2], a3 = assigns[p3];
        if (a0 != cur) { unsafeAtomicAdd(&sums[(size_t)cur * DIM + tid], acc); acc = 0.f; cur = a0; }
        acc += v0;
        if (a1 != cur) { unsafeAtomicAdd(&sums[(size_t)cur * DIM + tid], acc); acc = 0.f; cur = a1; }
        acc += v1;
        if (a2 != cur) { unsafeAtomicAdd(&sums[(size_t)cur * DIM + tid], acc); acc = 0.f; cur = a2; }
        acc += v2;
        if (a3 != cur) { unsafeAtomicAdd(&sums[(size_t)cur * DIM + tid], acc); acc = 0.f; cur = a3; }
        acc += v3;
    }
    unsafeAtomicAdd(&sums[(size_t)cur * DIM + tid], acc);
}

__global__ void finalize_kernel(const float* __restrict__ sums,
                                const int* __restrict__ hist,
                                const float* __restrict__ cen,
                                float* __restrict__ out) {
    const int id = blockIdx.x * 256 + threadIdx.x;   // KC*64 items
    const int k = id >> 6;
    const int cnt = hist[k];
    float4 s = ((const float4*)sums)[id];
    float4 c = ((const float4*)cen)[id];
    float4 o;
    if (cnt > 0) {
        float r = 1.0f / (float)cnt;
        o.x = s.x * r; o.y = s.y * r; o.z = s.z * r; o.w = s.w * r;
    } else {
        o = c;
    }
    ((float4*)out)[id] = o;
}

extern "C" void kernel_launch(void* const* d_in, const int* in_sizes, int n_in,
                              void* d_out, int out_size, void* d_ws, size_t ws_size,
                              hipStream_t stream) {
    (void)in_sizes; (void)n_in; (void)out_size; (void)ws_size;
    const float* x   = (const float*)d_in[0];
    const float* cen = (const float*)d_in[1];
    float* out = (float*)d_out;

    char* ws = (char*)d_ws;
    size_t off = 0;
    char* c_q = (char*)(ws + off);           off += (size_t)3 * KC * DIM;      // 1.5MB
    float* c_sq = (float*)(ws + off);        off += (size_t)KC * 4;            // 8KB
    int* assigns = (int*)(ws + off);         off += (size_t)NPTS * 4;          // 512KB
    int* hist = (int*)(ws + off);            off += (size_t)KC * 4;            // 8KB
    int* base_ = (int*)(ws + off);           off += (size_t)KC * 4;            // 8KB
    int* cursor = (int*)(ws + off);          off += (size_t)KC * 4;            // 8KB
    int* order = (int*)(ws + off);           off += (size_t)NPTS * 4;          // 512KB
    float* sums = (float*)(ws + off);        off += (size_t)KC * DIM * 4;      // 2MB
    u64* best_key = (u64*)(ws + off);        off += (size_t)NPTS * 8;          // 1MB

    hipMemsetAsync(sums, 0, (size_t)KC * DIM * sizeof(float), stream);
    hipMemsetAsync(best_key, 0xFF, (size_t)NPTS * sizeof(u64), stream);
    cprep_kernel<<<KC / 4, 256, 0, stream>>>(cen, c_q, c_sq, hist);
    assign_kernel<<<2 * NPTS / 128, 256, 0, stream>>>(x, c_q, c_sq, best_key);
    resolve_kernel<<<NPTS / 256, 256, 0, stream>>>(best_key, assigns, hist);
    scan_kernel<<<1, 256, 0, stream>>>(hist, base_, cursor);
    reorder_kernel<<<NPTS / 256, 256, 0, stream>>>(assigns, cursor, order);
    reduce_kernel<<<NPTS / 256, 256, 0, stream>>>(x, order, assigns, sums);
    finalize_kernel<<<KC * 64 / 256, 256, 0, stream>>>(sums, hist, cen, out);
}

// Round 2
// 615.307 us; speedup vs baseline: 1.1022x; 1.1022x over previous
//
#include <hip/hip_runtime.h>

typedef unsigned short u16;
typedef unsigned int u32;
typedef unsigned long long u64;
typedef __attribute__((ext_vector_type(4)))  int  i32x4;
typedef __attribute__((ext_vector_type(16))) int  i32x16;
typedef __attribute__((ext_vector_type(16))) char i8x16;

#define NPTS 131072
#define DIM  256
#define KC   2048

// 3-level fixed point: v = S1*q1 + S2*q2 + S3*q3 + eps, |eps| <= S3/2 ~ 4.8e-7
// Ratio 254 => rint(r*INV) in [-127,127]: no clamp cascade (q2/q3 clamps are
// mathematically redundant when q1 is in range: |r1| <= S1/2 -> |q2| <= 127).
// Identity S1*S3 == S2*S2 lets q2q2, q1q3, q3q1 share one accumulator.
constexpr float S1  = 0.0625f;                 // 127*S1 = 7.94 > max|N(0,1)|
constexpr float S2  = S1 / 254.0f;
constexpr float S3  = S2 * S2 / S1;            // = S2/254
constexpr float IS1 = 16.0f;
constexpr float IS2 = 4064.0f;                 // 254/S1
constexpr float IS3 = 1.0f / S3;
constexpr float W_A = S1 * S1;
// epilogue compares 254-scaled: v = csq254 - (254*A + B) - C/254
constexpr float R2  = 1.0f / 254.0f;

__device__ inline void quant3(float v, char& q1, char& q2, char& q3) {
    float a = fminf(fmaxf(rintf(v * IS1), -127.f), 127.f);
    float r1 = fmaf(-a, S1, v);                // exact (pow2 scale)
    float b = rintf(r1 * IS2);                 // |r1|<=S1/2 -> |b|<=127, no clamp
    float r2 = fmaf(-b, S2, r1);               // ~1-ulp error, absorbed by q3
    float c = rintf(r2 * IS3);                 // |r2|<=S2/2 -> |c|<=127
    q1 = (char)a; q2 = (char)b; q3 = (char)c;
}

// global -> LDS direct DMA, 16B per lane (wave-uniform base + lane*16)
#define GLD16(gsrc, ldst) \
    __builtin_amdgcn_global_load_lds( \
        (const __attribute__((address_space(1))) void*)(gsrc), \
        (__attribute__((address_space(3))) void*)(ldst), 16, 0, 0)

// ---------------------------------------------------------------------------
// Centroid prep: 3-level i8 split in MFMA-A-fragment order + int 254-scaled
// 0.5||c||^2. Per tile g (32 centroids): chunk s = dim/16,
// addr = ((g*16+s)*32+row)*16+b. Level l at byte offset l*KC*DIM.
// Also zeroes hist (blocks 0..7).
// ---------------------------------------------------------------------------
__global__ void cprep_kernel(const float* __restrict__ cen,
                             char* __restrict__ c_q,
                             int* __restrict__ c_sqi,
                             int* __restrict__ hist) {
    if (blockIdx.x < 8) hist[blockIdx.x * 256 + threadIdx.x] = 0;
    const int lane = threadIdx.x & 63;
    const int wv   = threadIdx.x >> 6;
    const int n    = blockIdx.x * 4 + wv;               // centroid row
    float4 v = ((const float4*)(cen + (size_t)n * DIM))[lane];  // dims lane*4..+3
    float ss = v.x * v.x + v.y * v.y + v.z * v.z + v.w * v.w;
    float fv[4] = {v.x, v.y, v.z, v.w};
    char q1[4], q2[4], q3[4];
#pragma unroll
    for (int j = 0; j < 4; ++j) quant3(fv[j], q1[j], q2[j], q3[j]);
    const int g = n >> 5, r32 = n & 31;
    const int s = lane >> 2;                             // chunk = dim/16
    const size_t base = ((size_t)((g * 16 + s) * 32 + r32)) * 16 + (lane & 3) * 4;
    u32 p1 = (u32)(unsigned char)q1[0] | ((u32)(unsigned char)q1[1] << 8) |
             ((u32)(unsigned char)q1[2] << 16) | ((u32)(unsigned char)q1[3] << 24);
    u32 p2 = (u32)(unsigned char)q2[0] | ((u32)(unsigned char)q2[1] << 8) |
             ((u32)(unsigned char)q2[2] << 16) | ((u32)(unsigned char)q2[3] << 24);
    u32 p3 = (u32)(unsigned char)q3[0] | ((u32)(unsigned char)q3[1] << 8) |
             ((u32)(unsigned char)q3[2] << 16) | ((u32)(unsigned char)q3[3] << 24);
    *(u32*)(c_q + base) = p1;
    *(u32*)(c_q + (size_t)KC * DIM + base) = p2;
    *(u32*)(c_q + (size_t)2 * KC * DIM + base) = p3;
#pragma unroll
    for (int off = 32; off > 0; off >>= 1) ss += __shfl_xor(ss, off);
    // 254-scaled int: 0.5*ss/W_A*254 = ss*32512; |.| <= ~1.5e7 (int-exact)
    if (lane == 0) c_sqi[n] = (int)rintf(ss * (0.5f * 254.0f / W_A));
}

// ---------------------------------------------------------------------------
// Assignment, counted-vmcnt pipeline (T3+T4): 3 LDS stage buffers of one
// HALF-tile each (32 cen x 128 dims x 3 levels = 12KB), one raw s_barrier per
// half-step, s_waitcnt vmcnt(3) (never 0 mid-loop) so 2 half-tiles of DMA stay
// in flight across barriers. csq table lives in LDS so the main loop has NO
// vmem besides the staging DMA (a global load in the epilogue would make the
// compiler drain the staging queue). Epilogue in 254-scaled int/float mix:
//   v = csq254 - (254*A + B) - C*R2   (mul24: |A| <= 4.13e6 < 2^23)
// ---------------------------------------------------------------------------
__global__ __launch_bounds__(256, 3) void assign_kernel(
    const float* __restrict__ x, const char* __restrict__ c_q,
    const int* __restrict__ c_sqi, int* __restrict__ assigns,
    int* __restrict__ hist) {
    __shared__ char lds_c[3 * 12288 + 8192];   // 3 stage bufs + csq table (44KB)

    const int tid  = threadIdx.x;
    const int lane = tid & 63;
    const int wv   = tid >> 6;
    const int l31  = lane & 31;
    const int kh   = lane >> 5;         // 16-dim half of the 32-dim k-tile

    const char* cl1 = c_q;
    const char* cl2 = c_q + (size_t)KC * DIM;
    const char* cl3 = c_q + (size_t)2 * KC * DIM;

    // ---- prologue DMA first (latency hidden under quantization VALU) ----
    GLD16((const char*)c_sqi + tid * 16,         lds_c + 36864 + tid * 16);
    GLD16((const char*)c_sqi + (tid + 256) * 16, lds_c + 36864 + (tid + 256) * 16);
    // stage(u=0) -> buf0, stage(u=1) -> buf1 (half-tile = 4KB per level)
    GLD16(cl1 + tid * 16,        lds_c + tid * 16);
    GLD16(cl2 + tid * 16,        lds_c + 4096 + tid * 16);
    GLD16(cl3 + tid * 16,        lds_c + 8192 + tid * 16);
    GLD16(cl1 + 4096 + tid * 16, lds_c + 12288 + tid * 16);
    GLD16(cl2 + 4096 + tid * 16, lds_c + 12288 + 4096 + tid * 16);
    GLD16(cl3 + 4096 + tid * 16, lds_c + 12288 + 8192 + tid * 16);

    // ---- quantize this lane's point (dims kt*32+kh*16 .. +15 per kt) ----
    const int m = blockIdx.x * 128 + wv * 32 + l31;
    const float4* xr = (const float4*)(x + (size_t)m * DIM);
    i8x16 xq1[8], xq2[8], xq3[8];
#pragma unroll
    for (int kt = 0; kt < 8; ++kt) {
        float tmp[16];
#pragma unroll
        for (int j = 0; j < 4; ++j) {
            float4 f = xr[kt * 8 + kh * 4 + j];
            tmp[j * 4 + 0] = f.x; tmp[j * 4 + 1] = f.y;
            tmp[j * 4 + 2] = f.z; tmp[j * 4 + 3] = f.w;
        }
        i8x16 v1, v2, v3;
#pragma unroll
        for (int j = 0; j < 16; ++j) {
            char a, b, c;
            quant3(tmp[j], a, b, c);
            v1[j] = a; v2[j] = b; v3[j] = c;
        }
        xq1[kt] = v1; xq2[kt] = v2; xq3[kt] = v3;
    }

    __syncthreads();   // full drain ONCE: stages 0,1 + csq table visible

    float best = 3.4e38f;
    int bidx = 0;
    int b3 = 0;        // current stage buffer (cycles 0,1,2)

    const int* csqL = (const int*)(lds_c + 36864);

    for (int t = 0; t < 64; ++t) {
        i32x16 accA = {}, accB = {}, accC = {};
#pragma unroll
        for (int h2 = 0; h2 < 2; ++h2) {
            // steady state: {stage(u), stage(u+1)} in flight (6 loads);
            // wait own stage(u) (leave 3), publish via barrier.
            if (t == 63 && h2 == 1) {
                asm volatile("s_waitcnt vmcnt(0)" ::: "memory");
            } else {
                asm volatile("s_waitcnt vmcnt(3)" ::: "memory");
            }
            __builtin_amdgcn_s_barrier();
            __builtin_amdgcn_sched_barrier(0);
            // issue stage(u+2) into buf (b3+2)%3 == buf (u-1)%3: all waves
            // finished reading it before this barrier (program order).
            if (2 * t + h2 + 2 < 128) {
                int pn = b3 + 2; if (pn >= 3) pn -= 3;
                char* d = lds_c + pn * 12288;
                const size_t so = (size_t)(2 * t + h2 + 2) * 4096;
                GLD16(cl1 + so + tid * 16, d + tid * 16);
                GLD16(cl2 + so + tid * 16, d + 4096 + tid * 16);
                GLD16(cl3 + so + tid * 16, d + 8192 + tid * 16);
            }
            const char* cb = lds_c + b3 * 12288;
            __builtin_amdgcn_s_setprio(1);
#pragma unroll
            for (int kt2 = 0; kt2 < 4; ++kt2) {
                const int off = kt2 * 1024 + kh * 512 + l31 * 16;
                i32x4 c1 = __builtin_bit_cast(i32x4, *(const i8x16*)(cb + off));
                i32x4 c2 = __builtin_bit_cast(i32x4, *(const i8x16*)(cb + 4096 + off));
                i32x4 c3 = __builtin_bit_cast(i32x4, *(const i8x16*)(cb + 8192 + off));
                i32x4 x1 = __builtin_bit_cast(i32x4, xq1[h2 * 4 + kt2]);
                i32x4 x2 = __builtin_bit_cast(i32x4, xq2[h2 * 4 + kt2]);
                i32x4 x3 = __builtin_bit_cast(i32x4, xq3[h2 * 4 + kt2]);
                // interleaved so same-accumulator MFMAs aren't back-to-back
                accA = __builtin_amdgcn_mfma_i32_32x32x32_i8(c1, x1, accA, 0, 0, 0);
                accB = __builtin_amdgcn_mfma_i32_32x32x32_i8(c1, x2, accB, 0, 0, 0);
                accC = __builtin_amdgcn_mfma_i32_32x32x32_i8(c2, x2, accC, 0, 0, 0);
                accB = __builtin_amdgcn_mfma_i32_32x32x32_i8(c2, x1, accB, 0, 0, 0);
                accC = __builtin_amdgcn_mfma_i32_32x32x32_i8(c1, x3, accC, 0, 0, 0);
                accC = __builtin_amdgcn_mfma_i32_32x32x32_i8(c3, x1, accC, 0, 0, 0);
            }
            __builtin_amdgcn_s_setprio(0);
            b3 += 1; if (b3 == 3) b3 = 0;
        }

        // epilogue: v = csq254 - (254*A + B) - C/254 (254x old score, same argmin)
        // D row = (reg&3)+8*(reg>>2)+4*kh
#pragma unroll
        for (int bq = 0; bq < 4; ++bq) {
            int4 cs = *(const int4*)(csqL + (t * 8 + 2 * bq + kh) * 4);
            const int n0 = t * 32 + 8 * bq + 4 * kh;
            int csa[4] = {cs.x, cs.y, cs.z, cs.w};
#pragma unroll
            for (int r = 0; r < 4; ++r) {
                const int idx = bq * 4 + r;
                int D  = __mul24(accA[idx], 254) + accB[idx];  // exact, |A|<2^23
                int Vi = csa[r] - D;                           // exact i32
                float v = fmaf((float)accC[idx], -R2, (float)Vi);
                if (v < best) { best = v; bidx = n0 + r; }
            }
        }
    }

    // merge the lane pair holding the other 16 centroid rows for point m
    float oval = __shfl_xor(best, 32);
    int   oidx = __shfl_xor(bidx, 32);
    if (oval < best || (oval == best && oidx < bidx)) { best = oval; bidx = oidx; }
    if (lane < 32) {
        assigns[m] = bidx;
        atomicAdd(&hist[bidx], 1);   // 128 atomics/block; LDS staging gains nothing
    }
}

// Exclusive prefix sum over KC=2048 counts; one block of 256 threads x 8 each.
__global__ void scan_kernel(const int* __restrict__ hist,
                            int* __restrict__ base_,
                            int* __restrict__ cursor) {
    __shared__ int tmp[256];
    const int tid = threadIdx.x;
    int v[8], s = 0;
#pragma unroll
    for (int j = 0; j < 8; ++j) { v[j] = hist[tid * 8 + j]; s += v[j]; }
    tmp[tid] = s;
    __syncthreads();
    for (int off = 1; off < 256; off <<= 1) {
        int t = (tid >= off) ? tmp[tid - off] : 0;
        __syncthreads();
        tmp[tid] += t;
        __syncthreads();
    }
    int ex = tmp[tid] - s;
#pragma unroll
    for (int j = 0; j < 8; ++j) {
        base_[tid * 8 + j] = ex;
        cursor[tid * 8 + j] = ex;
        ex += v[j];
    }
}

__global__ void reorder_kernel(const int* __restrict__ assigns,
                               int* __restrict__ cursor,
                               int* __restrict__ order) {
    const int p = blockIdx.x * 256 + threadIdx.x;
    const int a = assigns[p];
    int pos = atomicAdd(&cursor[a], 1);
    order[pos] = p;
}

// ---------------------------------------------------------------------------
// Skew-immune segmented reduce: each block owns 256 consecutive rows of the
// SORTED order array; thread t owns dim t (coalesced 1KB row reads). Flush to
// sums[] with atomics only at cluster boundaries (block-uniform branches).
// ---------------------------------------------------------------------------
__global__ void reduce_kernel(const float* __restrict__ x,
                              const int* __restrict__ order,
                              const int* __restrict__ assigns,
                              float* __restrict__ sums) {
    const int tid = threadIdx.x;
    const int r0 = blockIdx.x * 256;
    float acc = 0.f;
    int cur = assigns[order[r0]];
    for (int r = 0; r < 256; r += 4) {
        int p0 = order[r0 + r + 0], p1 = order[r0 + r + 1];
        int p2 = order[r0 + r + 2], p3 = order[r0 + r + 3];
        float v0 = x[(size_t)p0 * DIM + tid];
        float v1 = x[(size_t)p1 * DIM + tid];
        float v2 = x[(size_t)p2 * DIM + tid];
        float v3 = x[(size_t)p3 * DIM + tid];
        int a0 = assigns[p0], a1 = assigns[p1], a2 = assigns[p2], a3 = assigns[p3];
        if (a0 != cur) { unsafeAtomicAdd(&sums[(size_t)cur * DIM + tid], acc); acc = 0.f; cur = a0; }
        acc += v0;
        if (a1 != cur) { unsafeAtomicAdd(&sums[(size_t)cur * DIM + tid], acc); acc = 0.f; cur = a1; }
        acc += v1;
        if (a2 != cur) { unsafeAtomicAdd(&sums[(size_t)cur * DIM + tid], acc); acc = 0.f; cur = a2; }
        acc += v2;
        if (a3 != cur) { unsafeAtomicAdd(&sums[(size_t)cur * DIM + tid], acc); acc = 0.f; cur = a3; }
        acc += v3;
    }
    unsafeAtomicAdd(&sums[(size_t)cur * DIM + tid], acc);
}

__global__ void finalize_kernel(const float* __restrict__ sums,
                                const int* __restrict__ hist,
                                const float* __restrict__ cen,
                                float* __restrict__ out) {
    const int id = blockIdx.x * 256 + threadIdx.x;   // KC*64 items
    const int k = id >> 6;
    const int cnt = hist[k];
    float4 s = ((const float4*)sums)[id];
    float4 c = ((const float4*)cen)[id];
    float4 o;
    if (cnt > 0) {
        float r = 1.0f / (float)cnt;
        o.x = s.x * r; o.y = s.y * r; o.z = s.z * r; o.w = s.w * r;
    } else {
        o = c;
    }
    ((float4*)out)[id] = o;
}

extern "C" void kernel_launch(void* const* d_in, const int* in_sizes, int n_in,
                              void* d_out, int out_size, void* d_ws, size_t ws_size,
                              hipStream_t stream) {
    (void)in_sizes; (void)n_in; (void)out_size; (void)ws_size;
    const float* x   = (const float*)d_in[0];
    const float* cen = (const float*)d_in[1];
    float* out = (float*)d_out;

    char* ws = (char*)d_ws;
    size_t off = 0;
    char* c_q = (char*)(ws + off);           off += (size_t)3 * KC * DIM;      // 1.5MB
    int* c_sqi = (int*)(ws + off);           off += (size_t)KC * 4;            // 8KB
    int* assigns = (int*)(ws + off);         off += (size_t)NPTS * 4;          // 512KB
    int* hist = (int*)(ws + off);            off += (size_t)KC * 4;            // 8KB
    int* base_ = (int*)(ws + off);           off += (size_t)KC * 4;            // 8KB
    int* cursor = (int*)(ws + off);          off += (size_t)KC * 4;            // 8KB
    int* order = (int*)(ws + off);           off += (size_t)NPTS * 4;          // 512KB
    float* sums = (float*)(ws + off);        off += (size_t)KC * DIM * 4;      // 2MB

    hipMemsetAsync(sums, 0, (size_t)KC * DIM * sizeof(float), stream);
    cprep_kernel<<<KC / 4, 256, 0, stream>>>(cen, c_q, c_sqi, hist);
    assign_kernel<<<NPTS / 128, 256, 0, stream>>>(x, c_q, c_sqi, assigns, hist);
    scan_kernel<<<1, 256, 0, stream>>>(hist, base_, cursor);
    reorder_kernel<<<NPTS / 256, 256, 0, stream>>>(assigns, cursor, order);
    reduce_kernel<<<NPTS / 256, 256, 0, stream>>>(x, order, assigns, sums);
    finalize_kernel<<<KC * 64 / 256, 256, 0, stream>>>(sums, hist, cen, out);
}